// Round 2
// baseline (7557.129 us; speedup 1.0000x reference)
//
#include <hip/hip_runtime.h>

// Problem constants
constexpr int   kNU    = 40;
constexpr int   kNB    = 108;    // B_hat rows
constexpr int   kBATCH = 4096;
constexpr int   kITERS = 20;
constexpr float kSIGMA = 0.1f;
constexpr float kBIG   = 1e9f;
constexpr float kEPS   = 1e-4f;
constexpr int   BPST   = 48;     // padded row stride of permuted B_hat (stride-6 fragments)
constexpr int   QST    = 44;     // padded row stride of Q in LDS

// ---------------------------------------------------------------------------
// Kernel 1: build Q_hat [40x40], permuted B_hat [108x48], h [148]
// ---------------------------------------------------------------------------
__global__ void setup_kernel(const float* __restrict__ L, const float* __restrict__ LP,
                             const float* __restrict__ LR, const float* __restrict__ A,
                             const float* __restrict__ Bm, const float* __restrict__ u0,
                             const float* __restrict__ s0,
                             float* __restrict__ Qg, float* __restrict__ Bpg,
                             float* __restrict__ hg)
{
    __shared__ float sQx[144], sP[144], sR[16], sM[9][48];
    __shared__ float sBh[108 * 40], sQB[108 * 40];
    const int tid = threadIdx.x;

    for (int idx = tid; idx < 144; idx += 256) {
        int i = idx / 12, j = idx % 12, mn = (i < j) ? i : j;
        float a1 = 0.f, a2 = 0.f;
        for (int k = 0; k <= mn; ++k) {
            a1 = fmaf(L[i * 12 + k],  L[j * 12 + k],  a1);
            a2 = fmaf(LP[i * 12 + k], LP[j * 12 + k], a2);
        }
        if (i == j) { a1 += kEPS; a2 += kEPS; }
        sQx[idx] = a1; sP[idx] = a2;
    }
    if (tid < 16) {
        int i = tid / 4, j = tid % 4, mn = (i < j) ? i : j;
        float a = 0.f;
        for (int k = 0; k <= mn; ++k) a = fmaf(LR[i * 4 + k], LR[j * 4 + k], a);
        if (i == j) a += kEPS;
        sR[tid] = a;
    }
    if (tid < 48) sM[0][tid] = Bm[tid];
    __syncthreads();
    for (int r = 1; r < 9; ++r) {
        if (tid < 48) {
            int i = tid / 4, c = tid % 4;
            float acc = 0.f;
            for (int k = 0; k < 12; ++k) acc = fmaf(A[i * 12 + k], sM[r - 1][k * 4 + c], acc);
            sM[r][tid] = acc;
        }
        __syncthreads();
    }
    for (int idx = tid; idx < 108 * 40; idx += 256) {
        int j = idx / 40, i = idx % 40, r = j / 12, rr = j % 12, c = i / 4, cc = i % 4;
        sBh[idx] = (c <= r) ? sM[r - c][rr * 4 + cc] : 0.f;
    }
    __syncthreads();
    for (int idx = tid; idx < 108 * 40; idx += 256) {
        int j = idx / 40, i = idx % 40, r = j / 12, rr = j % 12;
        const float* Qb = (r < 8) ? sQx : sP;
        float acc = 0.f;
        for (int kk = 0; kk < 12; ++kk) acc = fmaf(Qb[rr * 12 + kk], sBh[(12 * r + kk) * 40 + i], acc);
        sQB[idx] = acc;
    }
    __syncthreads();
    for (int idx = tid; idx < 1600; idx += 256) {
        int i = idx / 40, k = idx % 40;
        float acc = 0.f;
        for (int j = 0; j < 108; ++j) acc = fmaf(sBh[j * 40 + i], sQB[j * 40 + k], acc);
        if (i / 4 == k / 4) acc += sR[(i % 4) * 4 + (k % 4)];
        Qg[idx] = acc;
    }
    // permuted/padded B_hat: slot m = li*6+a (a<5) <-> col = li + 8a ; a==5 is zero pad
    for (int idx = tid; idx < 108 * BPST; idx += 256) {
        int j = idx / BPST, m = idx % BPST, li2 = m / 6, a2 = m % 6;
        Bpg[idx] = (a2 < 5) ? sBh[j * 40 + li2 + 8 * a2] : 0.f;
    }
    for (int idx = tid; idx < 148; idx += 256) {
        float acc;
        if (idx < 40) acc = u0[idx];
        else {
            acc = 0.f;
            for (int i = 0; i < 40; ++i) acc = fmaf(sBh[(idx - 40) * 40 + i], u0[i], acc);
        }
        hg[idx] = acc + s0[idx];
    }
}

// ---------------------------------------------------------------------------
// Kernel 2: fused MLP
// ---------------------------------------------------------------------------
__global__ void mlp_kernel(const float* __restrict__ x, const float* __restrict__ W1,
                           const float* __restrict__ b1, const float* __restrict__ W2,
                           const float* __restrict__ b2, float* __restrict__ pg)
{
    const int b = blockIdx.x, t = threadIdx.x;
    float xr[12];
#pragma unroll
    for (int k = 0; k < 12; ++k) xr[k] = x[b * 12 + k];
    float hv[8];
#pragma unroll
    for (int q = 0; q < 8; ++q) {
        const int hh = q * 64 + t;
        float acc = b1[hh];
#pragma unroll
        for (int k = 0; k < 12; ++k) acc = fmaf(xr[k], W1[hh * 12 + k], acc);
        hv[q] = (acc >= 0.f) ? acc : 0.01f * acc;
    }
    for (int o = 0; o < 40; ++o) {
        float part = 0.f;
#pragma unroll
        for (int q = 0; q < 8; ++q) part = fmaf(hv[q], W2[o * 512 + q * 64 + t], part);
#pragma unroll
        for (int m = 32; m >= 1; m >>= 1) part += __shfl_xor(part, m, 64);
        if (t == o) {
            float v = part + b2[o];
            pg[b * 40 + o] = (v >= 0.f) ? v : 0.01f * v;
        }
    }
}

// ---------------------------------------------------------------------------
// Kernel 3: IPM — register Cholesky/solves in 2D lane layout, no in-loop barriers
// ---------------------------------------------------------------------------
__device__ __forceinline__ float waveSum(float v) {
#pragma unroll
    for (int m = 32; m >= 1; m >>= 1) v += __shfl_xor(v, m, 64);
    return v;
}
__device__ __forceinline__ float waveMin(float v) {
#pragma unroll
    for (int m = 32; m >= 1; m >>= 1) v = fminf(v, __shfl_xor(v, m, 64));
    return v;
}
__device__ __forceinline__ float rowdot48(const float* row, const float* v) {
    float acc = 0.f;
#pragma unroll
    for (int m = 0; m < 48; m += 4) {
        float4 a = *reinterpret_cast<const float4*>(row + m);
        float4 b = *reinterpret_cast<const float4*>(v + m);
        acc = fmaf(a.x, b.x, acc); acc = fmaf(a.y, b.y, acc);
        acc = fmaf(a.z, b.z, acc); acc = fmaf(a.w, b.w, acc);
    }
    return acc;
}

__global__ __launch_bounds__(256, 4) void ipm_kernel(
    const float* __restrict__ Qg, const float* __restrict__ Bpg,
    const float* __restrict__ hg, const float* __restrict__ pg,
    float* __restrict__ out)
{
    __shared__ __align__(16) float sBp[kNB * BPST];   // 20736 B (block-shared, RO)
    __shared__ __align__(16) float sQ[40 * QST];      //  7040 B (block-shared, RO)
    __shared__ float sLT[4][148];                     //  2368 B (per-wave)
    __shared__ float sD[4][148];                      //  2368 B
    __shared__ __align__(16) float sU[4][40];
    __shared__ __align__(16) float sUp[4][48];
    __shared__ __align__(16) float sDup[4][48];       // total 34688 B -> 4 blocks/CU

    const int tid = threadIdx.x;
    const int w = tid >> 6;
    const int t = tid & 63;
    const int e = blockIdx.x * 4 + w;

    for (int i = tid; i < kNB * BPST / 4; i += 256)
        reinterpret_cast<float4*>(sBp)[i] = reinterpret_cast<const float4*>(Bpg)[i];
    for (int i = tid; i < 40 * QST; i += 256) {
        int r = i / QST, c = i % QST;
        sQ[i] = (c < 40) ? Qg[r * 40 + c] : 0.f;
    }
    if (t < 8) { sUp[w][t * 6 + 5] = 0.f; sDup[w][t * 6 + 5] = 0.f; }
    __syncthreads();

    const int li = t & 7, lk = t >> 3;
    const int pp = li * 6 + lk;                       // slot of col t (valid t<40)

    float u_r = 0.f, du_r = 0.f;
    const float p_r = (t < 40) ? pg[e * 40 + t] : 0.f;
    const float h0 = hg[t], h1 = hg[64 + t], h2 = (t < 20) ? hg[128 + t] : 0.f;
    float s0 = 1.f, s1 = 1.f, s2 = 1.f, l0 = 1.f, l1 = 1.f, l2 = 1.f;

    float* lt_  = sLT[w];
    float* dd_  = sD[w];
    float* uu   = sU[w];
    float* up   = sUp[w];
    float* dup  = sDup[w];

#pragma unroll 1
    for (int it = 0; it < kITERS; ++it) {
        // (A) stage u
        if (t < 40) { uu[t] = u_r; up[pp] = u_r; }

        // (C) rp = G u + s - h
        float g0, g1, g2 = 0.f;
        if (t < 40) g0 = u_r; else g0 = rowdot48(&sBp[(t - 40) * BPST], up);
        g1 = rowdot48(&sBp[(t + 24) * BPST], up);
        if (t < 20) g2 = rowdot48(&sBp[(t + 88) * BPST], up);
        const float rp0 = g0 + s0 - h0, rp1 = g1 + s1 - h1, rp2 = g2 + s2 - h2;

        // (D) mu
        float part = s0 * l0 + s1 * l1 + ((t < 20) ? s2 * l2 : 0.f);
        const float mu = waveSum(part) * (1.f / 148.f);

        // (E) rc, d, lam+tmp
        const float is0 = 1.f / s0, is1 = 1.f / s1, is2 = 1.f / s2;
        const float rc0 = kSIGMA * mu - s0 * l0;
        const float rc1 = kSIGMA * mu - s1 * l1;
        const float rc2 = kSIGMA * mu - s2 * l2;
        const float t0 = (rc0 + l0 * rp0) * is0;
        const float t1 = (rc1 + l1 * rp1) * is1;
        const float t2 = (rc2 + l2 * rp2) * is2;
        lt_[t] = l0 + t0; lt_[64 + t] = l1 + t1; if (t < 20) lt_[128 + t] = l2 + t2;
        dd_[t] = l0 * is0; dd_[64 + t] = l1 * is1; if (t < 20) dd_[128 + t] = l2 * is2;

        // (F) rhs = -(p + uQ + (lam+tmp)G)
        float rhs_r = 0.f;
        if (t < 40) {
            float acc = p_r + l0 + t0;
            const float* qrow = &sQ[t * QST];
#pragma unroll
            for (int m = 0; m < 40; m += 4) {
                float4 q4 = *reinterpret_cast<const float4*>(qrow + m);
                float4 u4 = *reinterpret_cast<const float4*>(uu + m);
                acc = fmaf(q4.x, u4.x, acc); acc = fmaf(q4.y, u4.y, acc);
                acc = fmaf(q4.z, u4.z, acc); acc = fmaf(q4.w, u4.w, acc);
            }
#pragma unroll 4
            for (int j = 0; j < kNB; ++j)
                acc = fmaf(lt_[40 + j], sBp[j * BPST + pp], acc);
            rhs_r = -acc;
        }

        // (G) H = Q + diag(d[:40]) + B^T diag(d[40:]) B ; lower blocks a>=c only
        float A_[5][5];
#pragma unroll
        for (int a = 0; a < 5; ++a)
#pragma unroll
            for (int c = 0; c <= a; ++c)
                A_[a][c] = sQ[(li + 8 * a) * QST + (lk + 8 * c)];
        if (li == lk) {
#pragma unroll
            for (int a = 0; a < 5; ++a) A_[a][a] += dd_[li + 8 * a];
        }
#pragma unroll
        for (int g = 0; g < 5; ++g) {
            const int na = g + 1;
            const int lo = 24 * g;
            const int hi = (g < 4) ? 24 * (g + 1) : 108;
            for (int j = lo; j < hi; ++j) {
                const float ddj = dd_[40 + j];
                const float* br = &sBp[j * BPST];
                float bi[5], bk[5];
#pragma unroll
                for (int a = 0; a < na; ++a) { bi[a] = br[li * 6 + a]; bk[a] = br[lk * 6 + a]; }
#pragma unroll
                for (int a = 0; a < na; ++a) {
                    const float f = ddj * bi[a];
#pragma unroll
                    for (int c = 0; c <= a; ++c) A_[a][c] = fmaf(f, bk[c], A_[a][c]);
                }
            }
        }

        // (H) register Cholesky in 2D lane layout; diag stores 1/L[k][k]
#pragma unroll
        for (int kc = 0; kc < 5; ++kc) {
            for (int k8 = 0; k8 < 8; ++k8) {
                const int k = kc * 8 + k8;
                const float hkk = __shfl(A_[kc][kc], 9 * k8);
                float r = __builtin_amdgcn_rsqf(hkk);
                r = r * (1.5f - 0.5f * hkk * r * r);        // Newton -> fp32-accurate
                if (lk == k8) {
#pragma unroll
                    for (int a = kc; a < 5; ++a) A_[a][kc] *= r;
                    if (li == k8) A_[kc][kc] = r;
                }
                float colv[5], rowv[5];
#pragma unroll
                for (int a = kc; a < 5; ++a) {
                    colv[a] = __shfl(A_[a][kc], li + 8 * k8);
                    colv[a] = (li + 8 * a > k) ? colv[a] : 0.f;
                }
#pragma unroll
                for (int c = kc; c < 5; ++c) {
                    rowv[c] = __shfl(A_[c][kc], lk + 8 * k8);
                    rowv[c] = (lk + 8 * c > k) ? rowv[c] : 0.f;
                }
#pragma unroll
                for (int a = kc; a < 5; ++a)
#pragma unroll
                    for (int c = kc; c <= a; ++c)
                        A_[a][c] = fmaf(-colv[a], rowv[c], A_[a][c]);
            }
        }

        // (I) forward solve L y = rhs
        float r8[5], y8[5], acc[5];
#pragma unroll
        for (int a = 0; a < 5; ++a) { r8[a] = __shfl(rhs_r, li + 8 * a); acc[a] = 0.f; }
#pragma unroll
        for (int kc = 0; kc < 5; ++kc) {
            for (int k8 = 0; k8 < 8; ++k8) {
                float red = acc[kc];
                red += __shfl_xor(red, 8); red += __shfl_xor(red, 16); red += __shfl_xor(red, 32);
                const float yk = __shfl((r8[kc] - red) * A_[kc][kc], 9 * k8);
                if (lk == k8) {
#pragma unroll
                    for (int a = kc; a < 5; ++a) acc[a] = fmaf(A_[a][kc], yk, acc[a]);
                }
                if (li == k8) y8[kc] = yk;
            }
        }
        // backward solve L^T x = y ; lane t<40 captures du_t
        float bacc[5];
#pragma unroll
        for (int c = 0; c < 5; ++c) bacc[c] = 0.f;
#pragma unroll
        for (int jc = 4; jc >= 0; --jc) {
            for (int j8 = 7; j8 >= 0; --j8) {
                const int j = jc * 8 + j8;
                float red = bacc[jc];
                red += __shfl_xor(red, 1); red += __shfl_xor(red, 2); red += __shfl_xor(red, 4);
                const float xj = __shfl((y8[jc] - red) * A_[jc][jc], 9 * j8);
                if (li == j8) {
#pragma unroll
                    for (int c = 0; c <= jc; ++c) bacc[c] = fmaf(A_[jc][c], xj, bacc[c]);
                }
                if (t == j) du_r = xj;
            }
        }

        // (J) Gdu, ds, dlam, step, updates
        if (t < 40) dup[pp] = du_r;
        float q0, q1, q2 = 0.f;
        if (t < 40) q0 = du_r; else q0 = rowdot48(&sBp[(t - 40) * BPST], dup);
        q1 = rowdot48(&sBp[(t + 24) * BPST], dup);
        if (t < 20) q2 = rowdot48(&sBp[(t + 88) * BPST], dup);

        const float ds0 = -rp0 - q0, ds1 = -rp1 - q1, ds2 = -rp2 - q2;
        const float dl0 = (rc0 + l0 * (rp0 + q0)) * is0;
        const float dl1 = (rc1 + l1 * (rp1 + q1)) * is1;
        const float dl2 = (rc2 + l2 * (rp2 + q2)) * is2;

        float am = kBIG;
        am = fminf(am, (ds0 < 0.f) ? (-s0 / ds0) : kBIG);
        am = fminf(am, (dl0 < 0.f) ? (-l0 / dl0) : kBIG);
        am = fminf(am, (ds1 < 0.f) ? (-s1 / ds1) : kBIG);
        am = fminf(am, (dl1 < 0.f) ? (-l1 / dl1) : kBIG);
        if (t < 20) {
            am = fminf(am, (ds2 < 0.f) ? (-s2 / ds2) : kBIG);
            am = fminf(am, (dl2 < 0.f) ? (-l2 / dl2) : kBIG);
        }
        am = waveMin(am);
        const float alpha = fminf(1.f, 0.99f * am);

        if (t < 40) u_r = fmaf(alpha, du_r, u_r);
        s0 = fmaf(alpha, ds0, s0); l0 = fmaf(alpha, dl0, l0);
        s1 = fmaf(alpha, ds1, s1); l1 = fmaf(alpha, dl1, l1);
        if (t < 20) { s2 = fmaf(alpha, ds2, s2); l2 = fmaf(alpha, dl2, l2); }
    }

    // epilogue
    if (t < 40) uu[t] = u_r;
    float qv = 0.f;
    if (t < 40) {
        float uq = 0.f;
        const float* qrow = &sQ[t * QST];
#pragma unroll
        for (int m = 0; m < 40; m += 4) {
            float4 q4 = *reinterpret_cast<const float4*>(qrow + m);
            float4 u4 = *reinterpret_cast<const float4*>(uu + m);
            uq = fmaf(q4.x, u4.x, uq); uq = fmaf(q4.y, u4.y, uq);
            uq = fmaf(q4.z, u4.z, uq); uq = fmaf(q4.w, u4.w, uq);
        }
        qv = u_r * (0.5f * uq + p_r);
    }
    qv = waveSum(qv);
    if (t == 0) { out[e] = qv; out[kBATCH + e] = u_r; }
}

// ---------------------------------------------------------------------------
extern "C" void kernel_launch(void* const* d_in, const int* in_sizes, int n_in,
                              void* d_out, int out_size, void* d_ws, size_t ws_size,
                              hipStream_t stream) {
    const float* x  = (const float*)d_in[0];
    const float* W1 = (const float*)d_in[1];
    const float* b1 = (const float*)d_in[2];
    const float* W2 = (const float*)d_in[3];
    const float* b2 = (const float*)d_in[4];
    const float* L  = (const float*)d_in[5];
    const float* LP = (const float*)d_in[6];
    const float* LR = (const float*)d_in[7];
    const float* A  = (const float*)d_in[8];
    const float* Bm = (const float*)d_in[9];
    const float* u0 = (const float*)d_in[10];
    const float* s0 = (const float*)d_in[11];
    float* out = (float*)d_out;
    float* ws  = (float*)d_ws;

    float* Qg  = ws;           // 1600
    float* Bpg = ws + 1600;    // 108*48 = 5184
    float* hg  = ws + 6784;    // 148
    float* pg  = ws + 6944;    // 4096*40

    setup_kernel<<<1, 256, 0, stream>>>(L, LP, LR, A, Bm, u0, s0, Qg, Bpg, hg);
    mlp_kernel<<<kBATCH, 64, 0, stream>>>(x, W1, b1, W2, b2, pg);
    ipm_kernel<<<kBATCH / 4, 256, 0, stream>>>(Qg, Bpg, hg, pg, out);
}

// Round 3
// 1783.848 us; speedup vs baseline: 4.2364x; 4.2364x over previous
//
#include <hip/hip_runtime.h>

// Problem constants
constexpr int   kNU    = 40;
constexpr int   kNB    = 108;    // B_hat rows
constexpr int   kBATCH = 4096;
constexpr int   kITERS = 20;
constexpr float kSIGMA = 0.1f;
constexpr float kBIG   = 1e9f;
constexpr float kEPS   = 1e-4f;
constexpr int   BPST   = 48;     // padded row stride of permuted B_hat (stride-6 fragments)
constexpr int   QST    = 44;     // padded row stride of Q in LDS

// ---------------------------------------------------------------------------
// Kernel 1: build Q_hat [40x40], permuted B_hat [108x48], h [148]
// ---------------------------------------------------------------------------
__global__ void setup_kernel(const float* __restrict__ L, const float* __restrict__ LP,
                             const float* __restrict__ LR, const float* __restrict__ A,
                             const float* __restrict__ Bm, const float* __restrict__ u0,
                             const float* __restrict__ s0,
                             float* __restrict__ Qg, float* __restrict__ Bpg,
                             float* __restrict__ hg)
{
    __shared__ float sQx[144], sP[144], sR[16], sM[9][48];
    __shared__ float sBh[108 * 40], sQB[108 * 40];
    const int tid = threadIdx.x;

    for (int idx = tid; idx < 144; idx += 256) {
        int i = idx / 12, j = idx % 12, mn = (i < j) ? i : j;
        float a1 = 0.f, a2 = 0.f;
        for (int k = 0; k <= mn; ++k) {
            a1 = fmaf(L[i * 12 + k],  L[j * 12 + k],  a1);
            a2 = fmaf(LP[i * 12 + k], LP[j * 12 + k], a2);
        }
        if (i == j) { a1 += kEPS; a2 += kEPS; }
        sQx[idx] = a1; sP[idx] = a2;
    }
    if (tid < 16) {
        int i = tid / 4, j = tid % 4, mn = (i < j) ? i : j;
        float a = 0.f;
        for (int k = 0; k <= mn; ++k) a = fmaf(LR[i * 4 + k], LR[j * 4 + k], a);
        if (i == j) a += kEPS;
        sR[tid] = a;
    }
    if (tid < 48) sM[0][tid] = Bm[tid];
    __syncthreads();
    for (int r = 1; r < 9; ++r) {
        if (tid < 48) {
            int i = tid / 4, c = tid % 4;
            float acc = 0.f;
            for (int k = 0; k < 12; ++k) acc = fmaf(A[i * 12 + k], sM[r - 1][k * 4 + c], acc);
            sM[r][tid] = acc;
        }
        __syncthreads();
    }
    for (int idx = tid; idx < 108 * 40; idx += 256) {
        int j = idx / 40, i = idx % 40, r = j / 12, rr = j % 12, c = i / 4, cc = i % 4;
        sBh[idx] = (c <= r) ? sM[r - c][rr * 4 + cc] : 0.f;
    }
    __syncthreads();
    for (int idx = tid; idx < 108 * 40; idx += 256) {
        int j = idx / 40, i = idx % 40, r = j / 12, rr = j % 12;
        const float* Qb = (r < 8) ? sQx : sP;
        float acc = 0.f;
        for (int kk = 0; kk < 12; ++kk) acc = fmaf(Qb[rr * 12 + kk], sBh[(12 * r + kk) * 40 + i], acc);
        sQB[idx] = acc;
    }
    __syncthreads();
    for (int idx = tid; idx < 1600; idx += 256) {
        int i = idx / 40, k = idx % 40;
        float acc = 0.f;
        for (int j = 0; j < 108; ++j) acc = fmaf(sBh[j * 40 + i], sQB[j * 40 + k], acc);
        if (i / 4 == k / 4) acc += sR[(i % 4) * 4 + (k % 4)];
        Qg[idx] = acc;
    }
    // permuted/padded B_hat: slot m = li*6+a (a<5) <-> col = li + 8a ; a==5 is zero pad
    for (int idx = tid; idx < 108 * BPST; idx += 256) {
        int j = idx / BPST, m = idx % BPST, li2 = m / 6, a2 = m % 6;
        Bpg[idx] = (a2 < 5) ? sBh[j * 40 + li2 + 8 * a2] : 0.f;
    }
    for (int idx = tid; idx < 148; idx += 256) {
        float acc;
        if (idx < 40) acc = u0[idx];
        else {
            acc = 0.f;
            for (int i = 0; i < 40; ++i) acc = fmaf(sBh[(idx - 40) * 40 + i], u0[i], acc);
        }
        hg[idx] = acc + s0[idx];
    }
}

// ---------------------------------------------------------------------------
// Kernel 2: fused MLP
// ---------------------------------------------------------------------------
__global__ void mlp_kernel(const float* __restrict__ x, const float* __restrict__ W1,
                           const float* __restrict__ b1, const float* __restrict__ W2,
                           const float* __restrict__ b2, float* __restrict__ pg)
{
    const int b = blockIdx.x, t = threadIdx.x;
    float xr[12];
#pragma unroll
    for (int k = 0; k < 12; ++k) xr[k] = x[b * 12 + k];
    float hv[8];
#pragma unroll
    for (int q = 0; q < 8; ++q) {
        const int hh = q * 64 + t;
        float acc = b1[hh];
#pragma unroll
        for (int k = 0; k < 12; ++k) acc = fmaf(xr[k], W1[hh * 12 + k], acc);
        hv[q] = (acc >= 0.f) ? acc : 0.01f * acc;
    }
    for (int o = 0; o < 40; ++o) {
        float part = 0.f;
#pragma unroll
        for (int q = 0; q < 8; ++q) part = fmaf(hv[q], W2[o * 512 + q * 64 + t], part);
#pragma unroll
        for (int m = 32; m >= 1; m >>= 1) part += __shfl_xor(part, m, 64);
        if (t == o) {
            float v = part + b2[o];
            pg[b * 40 + o] = (v >= 0.f) ? v : 0.01f * v;
        }
    }
}

// ---------------------------------------------------------------------------
// Kernel 3: IPM — register Cholesky/solves in 2D lane layout, no in-loop barriers
// Lower-triangular tile held as exactly 15 registers (statically indexed).
// ---------------------------------------------------------------------------
__device__ __forceinline__ float waveSum(float v) {
#pragma unroll
    for (int m = 32; m >= 1; m >>= 1) v += __shfl_xor(v, m, 64);
    return v;
}
__device__ __forceinline__ float waveMin(float v) {
#pragma unroll
    for (int m = 32; m >= 1; m >>= 1) v = fminf(v, __shfl_xor(v, m, 64));
    return v;
}
__device__ __forceinline__ float rowdot48(const float* row, const float* v) {
    float acc = 0.f;
#pragma unroll
    for (int m = 0; m < 48; m += 4) {
        float4 a = *reinterpret_cast<const float4*>(row + m);
        float4 b = *reinterpret_cast<const float4*>(v + m);
        acc = fmaf(a.x, b.x, acc); acc = fmaf(a.y, b.y, acc);
        acc = fmaf(a.z, b.z, acc); acc = fmaf(a.w, b.w, acc);
    }
    return acc;
}

#define TRI(a, c) A_[((a) * ((a) + 1)) / 2 + (c)]   // a >= c, all indices static

__global__ __launch_bounds__(256, 3) void ipm_kernel(
    const float* __restrict__ Qg, const float* __restrict__ Bpg,
    const float* __restrict__ hg, const float* __restrict__ pg,
    float* __restrict__ out)
{
    __shared__ __align__(16) float sBp[kNB * BPST];   // 20736 B (block-shared, RO)
    __shared__ __align__(16) float sQ[40 * QST];      //  7040 B (block-shared, RO)
    __shared__ float sLT[4][148];                     //  2368 B (per-wave)
    __shared__ float sD[4][148];                      //  2368 B
    __shared__ __align__(16) float sU[4][40];
    __shared__ __align__(16) float sUp[4][48];
    __shared__ __align__(16) float sDup[4][48];       // total 34688 B

    const int tid = threadIdx.x;
    const int w = tid >> 6;
    const int t = tid & 63;
    const int e = blockIdx.x * 4 + w;

    for (int i = tid; i < kNB * BPST / 4; i += 256)
        reinterpret_cast<float4*>(sBp)[i] = reinterpret_cast<const float4*>(Bpg)[i];
    for (int i = tid; i < 40 * QST; i += 256) {
        int r = i / QST, c = i % QST;
        sQ[i] = (c < 40) ? Qg[r * 40 + c] : 0.f;
    }
    if (t < 8) { sUp[w][t * 6 + 5] = 0.f; sDup[w][t * 6 + 5] = 0.f; }
    __syncthreads();

    const int li = t & 7, lk = t >> 3;
    const int pp = li * 6 + lk;                       // slot of col t (valid t<40)

    float u_r = 0.f, du_r = 0.f;
    const float p_r = (t < 40) ? pg[e * 40 + t] : 0.f;
    const float h0 = hg[t], h1 = hg[64 + t], h2 = (t < 20) ? hg[128 + t] : 0.f;
    float s0 = 1.f, s1 = 1.f, s2 = 1.f, l0 = 1.f, l1 = 1.f, l2 = 1.f;

    float* lt_  = sLT[w];
    float* dd_  = sD[w];
    float* uu   = sU[w];
    float* up   = sUp[w];
    float* dup  = sDup[w];

#pragma unroll 1
    for (int it = 0; it < kITERS; ++it) {
        // (A) stage u
        if (t < 40) { uu[t] = u_r; up[pp] = u_r; }

        // (C) rp = G u + s - h
        float g0, g1, g2 = 0.f;
        if (t < 40) g0 = u_r; else g0 = rowdot48(&sBp[(t - 40) * BPST], up);
        g1 = rowdot48(&sBp[(t + 24) * BPST], up);
        if (t < 20) g2 = rowdot48(&sBp[(t + 88) * BPST], up);
        const float rp0 = g0 + s0 - h0, rp1 = g1 + s1 - h1, rp2 = g2 + s2 - h2;

        // (D) mu
        float part = s0 * l0 + s1 * l1 + ((t < 20) ? s2 * l2 : 0.f);
        const float mu = waveSum(part) * (1.f / 148.f);

        // (E) rc, d, lam+tmp
        const float is0 = 1.f / s0, is1 = 1.f / s1, is2 = 1.f / s2;
        const float rc0 = kSIGMA * mu - s0 * l0;
        const float rc1 = kSIGMA * mu - s1 * l1;
        const float rc2 = kSIGMA * mu - s2 * l2;
        const float t0 = (rc0 + l0 * rp0) * is0;
        const float t1 = (rc1 + l1 * rp1) * is1;
        const float t2 = (rc2 + l2 * rp2) * is2;
        lt_[t] = l0 + t0; lt_[64 + t] = l1 + t1; if (t < 20) lt_[128 + t] = l2 + t2;
        dd_[t] = l0 * is0; dd_[64 + t] = l1 * is1; if (t < 20) dd_[128 + t] = l2 * is2;

        // (F) rhs = -(p + uQ + (lam+tmp)G)
        float rhs_r = 0.f;
        if (t < 40) {
            float acc = p_r + l0 + t0;
            const float* qrow = &sQ[t * QST];
#pragma unroll
            for (int m = 0; m < 40; m += 4) {
                float4 q4 = *reinterpret_cast<const float4*>(qrow + m);
                float4 u4 = *reinterpret_cast<const float4*>(uu + m);
                acc = fmaf(q4.x, u4.x, acc); acc = fmaf(q4.y, u4.y, acc);
                acc = fmaf(q4.z, u4.z, acc); acc = fmaf(q4.w, u4.w, acc);
            }
#pragma unroll 4
            for (int j = 0; j < kNB; ++j)
                acc = fmaf(lt_[40 + j], sBp[j * BPST + pp], acc);
            rhs_r = -acc;
        }

        // (G) H = Q + diag(d[:40]) + B^T diag(d[40:]) B ; lower blocks a>=c only
        float A_[15];
#pragma unroll
        for (int a = 0; a < 5; ++a)
#pragma unroll
            for (int c = 0; c <= a; ++c)
                TRI(a, c) = sQ[(li + 8 * a) * QST + (lk + 8 * c)];
        if (li == lk) {
#pragma unroll
            for (int a = 0; a < 5; ++a) TRI(a, a) += dd_[li + 8 * a];
        }
#pragma unroll
        for (int g = 0; g < 5; ++g) {
            const int na = g + 1;
            const int lo = 24 * g;
            const int hi = (g < 4) ? 24 * (g + 1) : 108;
            for (int j = lo; j < hi; ++j) {
                const float ddj = dd_[40 + j];
                const float* br = &sBp[j * BPST];
                float bi[5], bk[5];
#pragma unroll
                for (int a = 0; a < na; ++a) { bi[a] = br[li * 6 + a]; bk[a] = br[lk * 6 + a]; }
#pragma unroll
                for (int a = 0; a < na; ++a) {
                    const float f = ddj * bi[a];
#pragma unroll
                    for (int c = 0; c <= a; ++c) TRI(a, c) = fmaf(f, bk[c], TRI(a, c));
                }
            }
        }

        // (H) register Cholesky in 2D lane layout; diag stores 1/L[k][k]
#pragma unroll
        for (int kc = 0; kc < 5; ++kc) {
            for (int k8 = 0; k8 < 8; ++k8) {
                const int k = kc * 8 + k8;
                const float hkk = __shfl(TRI(kc, kc), 9 * k8);
                float r = __builtin_amdgcn_rsqf(hkk);
                r = r * (1.5f - 0.5f * hkk * r * r);        // Newton -> fp32-accurate
                if (lk == k8) {
#pragma unroll
                    for (int a = kc; a < 5; ++a) TRI(a, kc) *= r;
                    if (li == k8) TRI(kc, kc) = r;
                }
                float colv[5], rowv[5];
#pragma unroll
                for (int a = kc; a < 5; ++a) {
                    colv[a] = __shfl(TRI(a, kc), li + 8 * k8);
                    colv[a] = (li + 8 * a > k) ? colv[a] : 0.f;
                }
#pragma unroll
                for (int c = kc; c < 5; ++c) {
                    rowv[c] = __shfl(TRI(c, kc), lk + 8 * k8);
                    rowv[c] = (lk + 8 * c > k) ? rowv[c] : 0.f;
                }
#pragma unroll
                for (int a = kc; a < 5; ++a)
#pragma unroll
                    for (int c = kc; c <= a; ++c)
                        TRI(a, c) = fmaf(-colv[a], rowv[c], TRI(a, c));
            }
        }

        // (I) forward solve L y = rhs
        float r8[5], y8[5], acc[5];
#pragma unroll
        for (int a = 0; a < 5; ++a) { r8[a] = __shfl(rhs_r, li + 8 * a); acc[a] = 0.f; }
#pragma unroll
        for (int kc = 0; kc < 5; ++kc) {
            for (int k8 = 0; k8 < 8; ++k8) {
                float red = acc[kc];
                red += __shfl_xor(red, 8); red += __shfl_xor(red, 16); red += __shfl_xor(red, 32);
                const float yk = __shfl((r8[kc] - red) * TRI(kc, kc), 9 * k8);
                if (lk == k8) {
#pragma unroll
                    for (int a = kc; a < 5; ++a) acc[a] = fmaf(TRI(a, kc), yk, acc[a]);
                }
                if (li == k8) y8[kc] = yk;
            }
        }
        // backward solve L^T x = y ; lane t<40 captures du_t
        float bacc[5];
#pragma unroll
        for (int c = 0; c < 5; ++c) bacc[c] = 0.f;
#pragma unroll
        for (int jc = 4; jc >= 0; --jc) {
            for (int j8 = 7; j8 >= 0; --j8) {
                const int j = jc * 8 + j8;
                float red = bacc[jc];
                red += __shfl_xor(red, 1); red += __shfl_xor(red, 2); red += __shfl_xor(red, 4);
                const float xj = __shfl((y8[jc] - red) * TRI(jc, jc), 9 * j8);
                if (li == j8) {
#pragma unroll
                    for (int c = 0; c <= jc; ++c) bacc[c] = fmaf(TRI(jc, c), xj, bacc[c]);
                }
                if (t == j) du_r = xj;
            }
        }

        // (J) Gdu, ds, dlam, step, updates
        if (t < 40) dup[pp] = du_r;
        float q0, q1, q2 = 0.f;
        if (t < 40) q0 = du_r; else q0 = rowdot48(&sBp[(t - 40) * BPST], dup);
        q1 = rowdot48(&sBp[(t + 24) * BPST], dup);
        if (t < 20) q2 = rowdot48(&sBp[(t + 88) * BPST], dup);

        const float ds0 = -rp0 - q0, ds1 = -rp1 - q1, ds2 = -rp2 - q2;
        const float dl0 = (rc0 + l0 * (rp0 + q0)) * is0;
        const float dl1 = (rc1 + l1 * (rp1 + q1)) * is1;
        const float dl2 = (rc2 + l2 * (rp2 + q2)) * is2;

        float am = kBIG;
        am = fminf(am, (ds0 < 0.f) ? (-s0 / ds0) : kBIG);
        am = fminf(am, (dl0 < 0.f) ? (-l0 / dl0) : kBIG);
        am = fminf(am, (ds1 < 0.f) ? (-s1 / ds1) : kBIG);
        am = fminf(am, (dl1 < 0.f) ? (-l1 / dl1) : kBIG);
        if (t < 20) {
            am = fminf(am, (ds2 < 0.f) ? (-s2 / ds2) : kBIG);
            am = fminf(am, (dl2 < 0.f) ? (-l2 / dl2) : kBIG);
        }
        am = waveMin(am);
        const float alpha = fminf(1.f, 0.99f * am);

        if (t < 40) u_r = fmaf(alpha, du_r, u_r);
        s0 = fmaf(alpha, ds0, s0); l0 = fmaf(alpha, dl0, l0);
        s1 = fmaf(alpha, ds1, s1); l1 = fmaf(alpha, dl1, l1);
        if (t < 20) { s2 = fmaf(alpha, ds2, s2); l2 = fmaf(alpha, dl2, l2); }
    }

    // epilogue
    if (t < 40) uu[t] = u_r;
    float qv = 0.f;
    if (t < 40) {
        float uq = 0.f;
        const float* qrow = &sQ[t * QST];
#pragma unroll
        for (int m = 0; m < 40; m += 4) {
            float4 q4 = *reinterpret_cast<const float4*>(qrow + m);
            float4 u4 = *reinterpret_cast<const float4*>(uu + m);
            uq = fmaf(q4.x, u4.x, uq); uq = fmaf(q4.y, u4.y, uq);
            uq = fmaf(q4.z, u4.z, uq); uq = fmaf(q4.w, u4.w, uq);
        }
        qv = u_r * (0.5f * uq + p_r);
    }
    qv = waveSum(qv);
    if (t == 0) { out[e] = qv; out[kBATCH + e] = u_r; }
}

// ---------------------------------------------------------------------------
extern "C" void kernel_launch(void* const* d_in, const int* in_sizes, int n_in,
                              void* d_out, int out_size, void* d_ws, size_t ws_size,
                              hipStream_t stream) {
    const float* x  = (const float*)d_in[0];
    const float* W1 = (const float*)d_in[1];
    const float* b1 = (const float*)d_in[2];
    const float* W2 = (const float*)d_in[3];
    const float* b2 = (const float*)d_in[4];
    const float* L  = (const float*)d_in[5];
    const float* LP = (const float*)d_in[6];
    const float* LR = (const float*)d_in[7];
    const float* A  = (const float*)d_in[8];
    const float* Bm = (const float*)d_in[9];
    const float* u0 = (const float*)d_in[10];
    const float* s0 = (const float*)d_in[11];
    float* out = (float*)d_out;
    float* ws  = (float*)d_ws;

    float* Qg  = ws;           // 1600
    float* Bpg = ws + 1600;    // 108*48 = 5184
    float* hg  = ws + 6784;    // 148
    float* pg  = ws + 6944;    // 4096*40

    setup_kernel<<<1, 256, 0, stream>>>(L, LP, LR, A, Bm, u0, s0, Qg, Bpg, hg);
    mlp_kernel<<<kBATCH, 64, 0, stream>>>(x, W1, b1, W2, b2, pg);
    ipm_kernel<<<kBATCH / 4, 256, 0, stream>>>(Qg, Bpg, hg, pg, out);
}

// Round 7
// 1334.145 us; speedup vs baseline: 5.6644x; 1.3371x over previous
//
#include <hip/hip_runtime.h>

// Problem constants
constexpr int   kNB    = 108;    // B_hat rows
constexpr int   kBATCH = 4096;
constexpr int   kITERS = 20;
constexpr float kSIGMA = 0.1f;
constexpr float kBIG   = 1e9f;
constexpr float kEPS   = 1e-4f;
constexpr int   BPST   = 48;     // padded row stride of permuted B_hat (6-slot fragments)
constexpr int   QST    = 44;     // padded row stride of Q in LDS

// ---------------------------------------------------------------------------
// Kernel 1: build Q_hat [40x40], permuted B_hat [108x48], h [148]
// ---------------------------------------------------------------------------
__global__ void setup_kernel(const float* __restrict__ L, const float* __restrict__ LP,
                             const float* __restrict__ LR, const float* __restrict__ A,
                             const float* __restrict__ Bm, const float* __restrict__ u0,
                             const float* __restrict__ s0,
                             float* __restrict__ Qg, float* __restrict__ Bpg,
                             float* __restrict__ hg)
{
    __shared__ float sQx[144], sP[144], sR[16], sM[9][48];
    __shared__ float sBh[108 * 40], sQB[108 * 40];
    const int tid = threadIdx.x;

    for (int idx = tid; idx < 144; idx += 256) {
        int i = idx / 12, j = idx % 12, mn = (i < j) ? i : j;
        float a1 = 0.f, a2 = 0.f;
        for (int k = 0; k <= mn; ++k) {
            a1 = fmaf(L[i * 12 + k],  L[j * 12 + k],  a1);
            a2 = fmaf(LP[i * 12 + k], LP[j * 12 + k], a2);
        }
        if (i == j) { a1 += kEPS; a2 += kEPS; }
        sQx[idx] = a1; sP[idx] = a2;
    }
    if (tid < 16) {
        int i = tid / 4, j = tid % 4, mn = (i < j) ? i : j;
        float a = 0.f;
        for (int k = 0; k <= mn; ++k) a = fmaf(LR[i * 4 + k], LR[j * 4 + k], a);
        if (i == j) a += kEPS;
        sR[tid] = a;
    }
    if (tid < 48) sM[0][tid] = Bm[tid];
    __syncthreads();
    for (int r = 1; r < 9; ++r) {
        if (tid < 48) {
            int i = tid / 4, c = tid % 4;
            float acc = 0.f;
            for (int k = 0; k < 12; ++k) acc = fmaf(A[i * 12 + k], sM[r - 1][k * 4 + c], acc);
            sM[r][tid] = acc;
        }
        __syncthreads();
    }
    for (int idx = tid; idx < 108 * 40; idx += 256) {
        int j = idx / 40, i = idx % 40, r = j / 12, rr = j % 12, c = i / 4, cc = i % 4;
        sBh[idx] = (c <= r) ? sM[r - c][rr * 4 + cc] : 0.f;
    }
    __syncthreads();
    for (int idx = tid; idx < 108 * 40; idx += 256) {
        int j = idx / 40, i = idx % 40, r = j / 12, rr = j % 12;
        const float* Qb = (r < 8) ? sQx : sP;
        float acc = 0.f;
        for (int kk = 0; kk < 12; ++kk) acc = fmaf(Qb[rr * 12 + kk], sBh[(12 * r + kk) * 40 + i], acc);
        sQB[idx] = acc;
    }
    __syncthreads();
    for (int idx = tid; idx < 1600; idx += 256) {
        int i = idx / 40, k = idx % 40;
        float acc = 0.f;
        for (int j = 0; j < 108; ++j) acc = fmaf(sBh[j * 40 + i], sQB[j * 40 + k], acc);
        if (i / 4 == k / 4) acc += sR[(i % 4) * 4 + (k % 4)];
        Qg[idx] = acc;
    }
    // permuted/padded B_hat: slot m = li*6+a (a<5) <-> col = li + 8a ; a==5 is zero pad
    for (int idx = tid; idx < 108 * BPST; idx += 256) {
        int j = idx / BPST, m = idx % BPST, li2 = m / 6, a2 = m % 6;
        Bpg[idx] = (a2 < 5) ? sBh[j * 40 + li2 + 8 * a2] : 0.f;
    }
    for (int idx = tid; idx < 148; idx += 256) {
        float acc;
        if (idx < 40) acc = u0[idx];
        else {
            acc = 0.f;
            for (int i = 0; i < 40; ++i) acc = fmaf(sBh[(idx - 40) * 40 + i], u0[i], acc);
        }
        hg[idx] = acc + s0[idx];
    }
}

// ---------------------------------------------------------------------------
// Kernel 2: fused MLP (one wave per row)
// ---------------------------------------------------------------------------
__global__ void mlp_kernel(const float* __restrict__ x, const float* __restrict__ W1,
                           const float* __restrict__ b1, const float* __restrict__ W2,
                           const float* __restrict__ b2, float* __restrict__ pg)
{
    const int b = blockIdx.x, t = threadIdx.x;
    float xr[12];
#pragma unroll
    for (int k = 0; k < 12; ++k) xr[k] = x[b * 12 + k];
    float hv[8];
#pragma unroll
    for (int q = 0; q < 8; ++q) {
        const int hh = q * 64 + t;
        float acc = b1[hh];
#pragma unroll
        for (int k = 0; k < 12; ++k) acc = fmaf(xr[k], W1[hh * 12 + k], acc);
        hv[q] = (acc >= 0.f) ? acc : 0.01f * acc;
    }
    for (int o = 0; o < 40; ++o) {
        float part = 0.f;
#pragma unroll
        for (int q = 0; q < 8; ++q) part = fmaf(hv[q], W2[o * 512 + q * 64 + t], part);
#pragma unroll
        for (int m = 32; m >= 1; m >>= 1) part += __shfl_xor(part, m, 64);
        if (t == o) {
            float v = part + b2[o];
            pg[b * 40 + o] = (v >= 0.f) ? v : 0.01f * v;
        }
    }
}

// ---------------------------------------------------------------------------
// Kernel 3: IPM — LDL^T (no sqrt) register factorization, guarded pivots
// ---------------------------------------------------------------------------
__device__ __forceinline__ float waveSum(float v) {
#pragma unroll
    for (int m = 32; m >= 1; m >>= 1) v += __shfl_xor(v, m, 64);
    return v;
}
__device__ __forceinline__ float waveMin(float v) {
#pragma unroll
    for (int m = 32; m >= 1; m >>= 1) v = fminf(v, __shfl_xor(v, m, 64));
    return v;
}
__device__ __forceinline__ float rowdot48(const float* row, const float* v) {
    float acc = 0.f;
#pragma unroll
    for (int m = 0; m < 48; m += 4) {
        float4 a = *reinterpret_cast<const float4*>(row + m);
        float4 b = *reinterpret_cast<const float4*>(v + m);
        acc = fmaf(a.x, b.x, acc); acc = fmaf(a.y, b.y, acc);
        acc = fmaf(a.z, b.z, acc); acc = fmaf(a.w, b.w, acc);
    }
    return acc;
}
__device__ __forceinline__ float readlane_f(float v, int lane) {
    return __int_as_float(__builtin_amdgcn_readlane(__float_as_int(v), lane));
}
// guarded reciprocal: sign-preserving magnitude floor; exact IEEE divide.
// True pivots of the SPD H are >= ~1e-4; floor only catches rounding-crossed
// near-zero pivots so no inf/NaN can ever form.
__device__ __forceinline__ float safe_rcp(float piv) {
    float ps = (fabsf(piv) > 1e-12f) ? piv : ((piv >= 0.f) ? 1e-12f : -1e-12f);
    return 1.0f / ps;
}

#define TRI(a, c) A_[((a) * ((a) + 1)) / 2 + (c)]   // a >= c, static indices

__global__ __launch_bounds__(256, 3) void ipm_kernel(
    const float* __restrict__ Qg, const float* __restrict__ Bpg,
    const float* __restrict__ hg, const float* __restrict__ pg,
    float* __restrict__ out)
{
    __shared__ __align__(16) float sBp[kNB * BPST];   // 20736 B (block-shared, RO)
    __shared__ __align__(16) float sQ[40 * QST];      //  7040 B (block-shared, RO)
    __shared__ float sLT[4][148];                     //  2368 B (per-wave)
    __shared__ float sD[4][148];                      //  2368 B
    __shared__ __align__(16) float sU[4][40];
    __shared__ __align__(16) float sUp[4][48];
    __shared__ __align__(16) float sDup[4][48];       // total 34688 B

    const int tid = threadIdx.x;
    const int w = tid >> 6;
    const int t = tid & 63;
    const int e = blockIdx.x * 4 + w;

    for (int i = tid; i < kNB * BPST / 4; i += 256)
        reinterpret_cast<float4*>(sBp)[i] = reinterpret_cast<const float4*>(Bpg)[i];
    for (int i = tid; i < 40 * QST; i += 256) {
        int r = i / QST, c = i % QST;
        sQ[i] = (c < 40) ? Qg[r * 40 + c] : 0.f;
    }
    if (t < 8) { sUp[w][t * 6 + 5] = 0.f; sDup[w][t * 6 + 5] = 0.f; }
    __syncthreads();

    const int li = t & 7, lk = t >> 3;
    const int pp = li * 6 + lk;                       // slot of col t (valid t<40)

    float u_r = 0.f, du_r = 0.f;
    const float p_r = (t < 40) ? pg[e * 40 + t] : 0.f;
    const float h0 = hg[t], h1 = hg[64 + t], h2 = (t < 20) ? hg[128 + t] : 0.f;
    float s0 = 1.f, s1 = 1.f, s2 = 1.f, l0 = 1.f, l1 = 1.f, l2 = 1.f;

    float* lt_  = sLT[w];
    float* dd_  = sD[w];
    float* uu   = sU[w];
    float* up   = sUp[w];
    float* dup  = sDup[w];

#pragma unroll 1
    for (int it = 0; it < kITERS; ++it) {
        // (A) stage u
        if (t < 40) { uu[t] = u_r; up[pp] = u_r; }

        // (C) rp = G u + s - h
        float g0, g1, g2 = 0.f;
        if (t < 40) g0 = u_r; else g0 = rowdot48(&sBp[(t - 40) * BPST], up);
        g1 = rowdot48(&sBp[(t + 24) * BPST], up);
        if (t < 20) g2 = rowdot48(&sBp[(t + 88) * BPST], up);
        const float rp0 = g0 + s0 - h0, rp1 = g1 + s1 - h1, rp2 = g2 + s2 - h2;

        // (D) mu
        float part = s0 * l0 + s1 * l1 + ((t < 20) ? s2 * l2 : 0.f);
        const float mu = waveSum(part) * (1.f / 148.f);

        // (E) rc, d, lam+tmp   (exact IEEE division; round-3 numerics verbatim)
        const float is0 = 1.f / s0, is1 = 1.f / s1, is2 = 1.f / s2;
        const float rc0 = kSIGMA * mu - s0 * l0;
        const float rc1 = kSIGMA * mu - s1 * l1;
        const float rc2 = kSIGMA * mu - s2 * l2;
        const float t0 = (rc0 + l0 * rp0) * is0;
        const float t1 = (rc1 + l1 * rp1) * is1;
        const float t2 = (rc2 + l2 * rp2) * is2;
        lt_[t] = l0 + t0; lt_[64 + t] = l1 + t1; if (t < 20) lt_[128 + t] = l2 + t2;
        dd_[t] = l0 * is0; dd_[64 + t] = l1 * is1; if (t < 20) dd_[128 + t] = l2 * is2;

        // (F) rhs = -(p + uQ + (lam+tmp)G)
        float rhs_r = 0.f;
        if (t < 40) {
            float acc = p_r + l0 + t0;
            const float* qrow = &sQ[t * QST];
#pragma unroll
            for (int m = 0; m < 40; m += 4) {
                float4 q4 = *reinterpret_cast<const float4*>(qrow + m);
                float4 u4 = *reinterpret_cast<const float4*>(uu + m);
                acc = fmaf(q4.x, u4.x, acc); acc = fmaf(q4.y, u4.y, acc);
                acc = fmaf(q4.z, u4.z, acc); acc = fmaf(q4.w, u4.w, acc);
            }
#pragma unroll 4
            for (int j = 0; j < kNB; ++j)
                acc = fmaf(lt_[40 + j], sBp[j * BPST + pp], acc);
            rhs_r = -acc;
        }

        // (G) H = Q + diag(d[:40]) + B^T diag(d[40:]) B ; lower blocks a>=c only
        float A_[15];
#pragma unroll
        for (int a = 0; a < 5; ++a)
#pragma unroll
            for (int c = 0; c <= a; ++c)
                TRI(a, c) = sQ[(li + 8 * a) * QST + (lk + 8 * c)];
        if (li == lk) {
#pragma unroll
            for (int a = 0; a < 5; ++a) TRI(a, a) += dd_[li + 8 * a];
        }
#pragma unroll
        for (int g = 0; g < 5; ++g) {
            const int na = g + 1;
            const int lo = 24 * g;
            const int hi = (g < 4) ? 24 * (g + 1) : 108;
#pragma unroll 4
            for (int j = lo; j < hi; ++j) {
                const float ddj = dd_[40 + j];
                const float* br = &sBp[j * BPST];
                float bi[5], bk[5];
#pragma unroll
                for (int a = 0; a < na; ++a) { bi[a] = br[li * 6 + a]; bk[a] = br[lk * 6 + a]; }
#pragma unroll
                for (int a = 0; a < na; ++a) {
                    const float f = ddj * bi[a];
#pragma unroll
                    for (int c = 0; c <= a; ++c) TRI(a, c) = fmaf(f, bk[c], TRI(a, c));
                }
            }
        }

        // (H) register LDL^T in 2D lane layout. Columns stay RAW (= L*d);
        // the k-th diagonal (at lane (k8,k8)) is overwritten with r = 1/d_k.
#pragma unroll
        for (int kc = 0; kc < 5; ++kc) {
#pragma unroll 1
            for (int k8 = 0; k8 < 8; ++k8) {
                const float piv = readlane_f(TRI(kc, kc), 9 * k8);
                const float r = safe_rcp(piv);
                float colv[5], rowv[5];
#pragma unroll
                for (int a = kc; a < 5; ++a) colv[a] = __shfl(TRI(a, kc), li + 8 * k8, 64);
#pragma unroll
                for (int c = kc; c < 5; ++c) rowv[c] = __shfl(TRI(c, kc), lk + 8 * k8, 64);
                colv[kc] = (li > k8) ? colv[kc] : 0.f;   // rows  <= k give no update
                rowv[kc] = (lk > k8) ? rowv[kc] : 0.f;   // cols  <= k stay raw
#pragma unroll
                for (int c = kc; c < 5; ++c) rowv[c] *= r;
#pragma unroll
                for (int a = kc; a < 5; ++a)
#pragma unroll
                    for (int c = kc; c <= a; ++c)
                        TRI(a, c) = fmaf(-colv[a], rowv[c], TRI(a, c));
                if (li == k8 && lk == k8) TRI(kc, kc) = r;
            }
        }

        // (I) forward solve: y_k = rhs_k - sum_{j<k} raw_kj * w_j ; w_k = y_k * r_k
        float r8[5], y8[5], fa[5];
#pragma unroll
        for (int a = 0; a < 5; ++a) { r8[a] = __shfl(rhs_r, li + 8 * a, 64); fa[a] = 0.f; }
#pragma unroll
        for (int kc = 0; kc < 5; ++kc) {
#pragma unroll 1
            for (int k8 = 0; k8 < 8; ++k8) {
                float red = fa[kc];
                red += __shfl_xor(red, 8); red += __shfl_xor(red, 16); red += __shfl_xor(red, 32);
                const float wk = readlane_f((r8[kc] - red) * TRI(kc, kc), 9 * k8);
                if (lk == k8) {
#pragma unroll
                    for (int a = kc; a < 5; ++a) fa[a] = fmaf(TRI(a, kc), wk, fa[a]);
                }
                if (li == k8) y8[kc] = wk;               // stores w_k (= y_k / d_k)
            }
        }
        // backward solve: x_j = w_j - r_j * sum_{i>j} raw_ij * x_i
        float ba[5];
#pragma unroll
        for (int c = 0; c < 5; ++c) ba[c] = 0.f;
#pragma unroll
        for (int jc = 4; jc >= 0; --jc) {
#pragma unroll 1
            for (int j8 = 7; j8 >= 0; --j8) {
                float red = ba[jc];
                red += __shfl_xor(red, 1); red += __shfl_xor(red, 2); red += __shfl_xor(red, 4);
                const float xj = readlane_f(fmaf(-TRI(jc, jc), red, y8[jc]), 9 * j8);
                if (li == j8) {
#pragma unroll
                    for (int c = 0; c <= jc; ++c) ba[c] = fmaf(TRI(jc, c), xj, ba[c]);
                }
                if (t == jc * 8 + j8) du_r = xj;
            }
        }

        // (J) Gdu, ds, dlam, step, updates (round-3 numerics verbatim)
        if (t < 40) dup[pp] = du_r;
        float q0, q1, q2 = 0.f;
        if (t < 40) q0 = du_r; else q0 = rowdot48(&sBp[(t - 40) * BPST], dup);
        q1 = rowdot48(&sBp[(t + 24) * BPST], dup);
        if (t < 20) q2 = rowdot48(&sBp[(t + 88) * BPST], dup);

        const float ds0 = -rp0 - q0, ds1 = -rp1 - q1, ds2 = -rp2 - q2;
        const float dl0 = (rc0 + l0 * (rp0 + q0)) * is0;
        const float dl1 = (rc1 + l1 * (rp1 + q1)) * is1;
        const float dl2 = (rc2 + l2 * (rp2 + q2)) * is2;

        float am = kBIG;
        am = fminf(am, (ds0 < 0.f) ? (-s0 / ds0) : kBIG);
        am = fminf(am, (dl0 < 0.f) ? (-l0 / dl0) : kBIG);
        am = fminf(am, (ds1 < 0.f) ? (-s1 / ds1) : kBIG);
        am = fminf(am, (dl1 < 0.f) ? (-l1 / dl1) : kBIG);
        if (t < 20) {
            am = fminf(am, (ds2 < 0.f) ? (-s2 / ds2) : kBIG);
            am = fminf(am, (dl2 < 0.f) ? (-l2 / dl2) : kBIG);
        }
        am = waveMin(am);
        const float alpha = fminf(1.f, 0.99f * am);

        if (t < 40) u_r = fmaf(alpha, du_r, u_r);
        s0 = fmaf(alpha, ds0, s0); l0 = fmaf(alpha, dl0, l0);
        s1 = fmaf(alpha, ds1, s1); l1 = fmaf(alpha, dl1, l1);
        if (t < 20) { s2 = fmaf(alpha, ds2, s2); l2 = fmaf(alpha, dl2, l2); }
    }

    // epilogue
    if (t < 40) uu[t] = u_r;
    float qv = 0.f;
    if (t < 40) {
        float uq = 0.f;
        const float* qrow = &sQ[t * QST];
#pragma unroll
        for (int m = 0; m < 40; m += 4) {
            float4 q4 = *reinterpret_cast<const float4*>(qrow + m);
            float4 u4 = *reinterpret_cast<const float4*>(uu + m);
            uq = fmaf(q4.x, u4.x, uq); uq = fmaf(q4.y, u4.y, uq);
            uq = fmaf(q4.z, u4.z, uq); uq = fmaf(q4.w, u4.w, uq);
        }
        qv = u_r * (0.5f * uq + p_r);
    }
    qv = waveSum(qv);
    if (t == 0) { out[e] = qv; out[kBATCH + e] = u_r; }
}

// ---------------------------------------------------------------------------
extern "C" void kernel_launch(void* const* d_in, const int* in_sizes, int n_in,
                              void* d_out, int out_size, void* d_ws, size_t ws_size,
                              hipStream_t stream) {
    const float* x  = (const float*)d_in[0];
    const float* W1 = (const float*)d_in[1];
    const float* b1 = (const float*)d_in[2];
    const float* W2 = (const float*)d_in[3];
    const float* b2 = (const float*)d_in[4];
    const float* L  = (const float*)d_in[5];
    const float* LP = (const float*)d_in[6];
    const float* LR = (const float*)d_in[7];
    const float* A  = (const float*)d_in[8];
    const float* Bm = (const float*)d_in[9];
    const float* u0 = (const float*)d_in[10];
    const float* s0 = (const float*)d_in[11];
    float* out = (float*)d_out;
    float* ws  = (float*)d_ws;

    float* Qg  = ws;           // 1600
    float* Bpg = ws + 1600;    // 108*48 = 5184
    float* hg  = ws + 6784;    // 148
    float* pg  = ws + 6944;    // 4096*40

    setup_kernel<<<1, 256, 0, stream>>>(L, LP, LR, A, Bm, u0, s0, Qg, Bpg, hg);
    mlp_kernel<<<kBATCH, 64, 0, stream>>>(x, W1, b1, W2, b2, pg);
    ipm_kernel<<<kBATCH / 4, 256, 0, stream>>>(Qg, Bpg, hg, pg, out);
}

// Round 8
// 1148.739 us; speedup vs baseline: 6.5786x; 1.1614x over previous
//
#include <hip/hip_runtime.h>

// Problem constants
constexpr int   kNB    = 108;    // B_hat rows
constexpr int   kBATCH = 4096;
constexpr int   kITERS = 20;
constexpr float kSIGMA = 0.1f;
constexpr float kBIG   = 1e9f;
constexpr float kEPS   = 1e-4f;
constexpr int   BPST   = 48;     // padded row stride of permuted B_hat (6-slot fragments)
constexpr int   QST    = 44;     // padded row stride of Q in LDS

// ---------------------------------------------------------------------------
// Kernel 1: build Q_hat [40x40], permuted B_hat [108x48], h [148]
// ---------------------------------------------------------------------------
__global__ void setup_kernel(const float* __restrict__ L, const float* __restrict__ LP,
                             const float* __restrict__ LR, const float* __restrict__ A,
                             const float* __restrict__ Bm, const float* __restrict__ u0,
                             const float* __restrict__ s0,
                             float* __restrict__ Qg, float* __restrict__ Bpg,
                             float* __restrict__ hg)
{
    __shared__ float sQx[144], sP[144], sR[16], sM[9][48];
    __shared__ float sBh[108 * 40], sQB[108 * 40];
    const int tid = threadIdx.x;

    for (int idx = tid; idx < 144; idx += 256) {
        int i = idx / 12, j = idx % 12, mn = (i < j) ? i : j;
        float a1 = 0.f, a2 = 0.f;
        for (int k = 0; k <= mn; ++k) {
            a1 = fmaf(L[i * 12 + k],  L[j * 12 + k],  a1);
            a2 = fmaf(LP[i * 12 + k], LP[j * 12 + k], a2);
        }
        if (i == j) { a1 += kEPS; a2 += kEPS; }
        sQx[idx] = a1; sP[idx] = a2;
    }
    if (tid < 16) {
        int i = tid / 4, j = tid % 4, mn = (i < j) ? i : j;
        float a = 0.f;
        for (int k = 0; k <= mn; ++k) a = fmaf(LR[i * 4 + k], LR[j * 4 + k], a);
        if (i == j) a += kEPS;
        sR[tid] = a;
    }
    if (tid < 48) sM[0][tid] = Bm[tid];
    __syncthreads();
    for (int r = 1; r < 9; ++r) {
        if (tid < 48) {
            int i = tid / 4, c = tid % 4;
            float acc = 0.f;
            for (int k = 0; k < 12; ++k) acc = fmaf(A[i * 12 + k], sM[r - 1][k * 4 + c], acc);
            sM[r][tid] = acc;
        }
        __syncthreads();
    }
    for (int idx = tid; idx < 108 * 40; idx += 256) {
        int j = idx / 40, i = idx % 40, r = j / 12, rr = j % 12, c = i / 4, cc = i % 4;
        sBh[idx] = (c <= r) ? sM[r - c][rr * 4 + cc] : 0.f;
    }
    __syncthreads();
    for (int idx = tid; idx < 108 * 40; idx += 256) {
        int j = idx / 40, i = idx % 40, r = j / 12, rr = j % 12;
        const float* Qb = (r < 8) ? sQx : sP;
        float acc = 0.f;
        for (int kk = 0; kk < 12; ++kk) acc = fmaf(Qb[rr * 12 + kk], sBh[(12 * r + kk) * 40 + i], acc);
        sQB[idx] = acc;
    }
    __syncthreads();
    for (int idx = tid; idx < 1600; idx += 256) {
        int i = idx / 40, k = idx % 40;
        float acc = 0.f;
        for (int j = 0; j < 108; ++j) acc = fmaf(sBh[j * 40 + i], sQB[j * 40 + k], acc);
        if (i / 4 == k / 4) acc += sR[(i % 4) * 4 + (k % 4)];
        Qg[idx] = acc;
    }
    // permuted/padded B_hat: slot m = li*6+a (a<5) <-> col = li + 8a ; a==5 is zero pad
    for (int idx = tid; idx < 108 * BPST; idx += 256) {
        int j = idx / BPST, m = idx % BPST, li2 = m / 6, a2 = m % 6;
        Bpg[idx] = (a2 < 5) ? sBh[j * 40 + li2 + 8 * a2] : 0.f;
    }
    for (int idx = tid; idx < 148; idx += 256) {
        float acc;
        if (idx < 40) acc = u0[idx];
        else {
            acc = 0.f;
            for (int i = 0; i < 40; ++i) acc = fmaf(sBh[(idx - 40) * 40 + i], u0[i], acc);
        }
        hg[idx] = acc + s0[idx];
    }
}

// ---------------------------------------------------------------------------
// Kernel 2: fused MLP (one wave per row)
// ---------------------------------------------------------------------------
__global__ void mlp_kernel(const float* __restrict__ x, const float* __restrict__ W1,
                           const float* __restrict__ b1, const float* __restrict__ W2,
                           const float* __restrict__ b2, float* __restrict__ pg)
{
    const int b = blockIdx.x, t = threadIdx.x;
    float xr[12];
#pragma unroll
    for (int k = 0; k < 12; ++k) xr[k] = x[b * 12 + k];
    float hv[8];
#pragma unroll
    for (int q = 0; q < 8; ++q) {
        const int hh = q * 64 + t;
        float acc = b1[hh];
#pragma unroll
        for (int k = 0; k < 12; ++k) acc = fmaf(xr[k], W1[hh * 12 + k], acc);
        hv[q] = (acc >= 0.f) ? acc : 0.01f * acc;
    }
    for (int o = 0; o < 40; ++o) {
        float part = 0.f;
#pragma unroll
        for (int q = 0; q < 8; ++q) part = fmaf(hv[q], W2[o * 512 + q * 64 + t], part);
#pragma unroll
        for (int m = 32; m >= 1; m >>= 1) part += __shfl_xor(part, m, 64);
        if (t == o) {
            float v = part + b2[o];
            pg[b * 40 + o] = (v >= 0.f) ? v : 0.01f * v;
        }
    }
}

// ---------------------------------------------------------------------------
// Kernel 3: IPM — LDL^T (no sqrt) register factorization, guarded pivots
// ---------------------------------------------------------------------------
__device__ __forceinline__ float waveSum(float v) {
#pragma unroll
    for (int m = 32; m >= 1; m >>= 1) v += __shfl_xor(v, m, 64);
    return v;
}
__device__ __forceinline__ float waveMin(float v) {
#pragma unroll
    for (int m = 32; m >= 1; m >>= 1) v = fminf(v, __shfl_xor(v, m, 64));
    return v;
}
__device__ __forceinline__ float rowdot48(const float* row, const float* v) {
    float acc = 0.f;
#pragma unroll
    for (int m = 0; m < 48; m += 4) {
        float4 a = *reinterpret_cast<const float4*>(row + m);
        float4 b = *reinterpret_cast<const float4*>(v + m);
        acc = fmaf(a.x, b.x, acc); acc = fmaf(a.y, b.y, acc);
        acc = fmaf(a.z, b.z, acc); acc = fmaf(a.w, b.w, acc);
    }
    return acc;
}
__device__ __forceinline__ float readlane_f(float v, int lane) {
    return __int_as_float(__builtin_amdgcn_readlane(__float_as_int(v), lane));
}
// guarded reciprocal: sign-preserving magnitude floor; exact IEEE divide.
// True pivots of the SPD H are >= ~1e-4; floor only catches rounding-crossed
// near-zero pivots so no inf/NaN can ever form.
__device__ __forceinline__ float safe_rcp(float piv) {
    float ps = (fabsf(piv) > 1e-12f) ? piv : ((piv >= 0.f) ? 1e-12f : -1e-12f);
    return 1.0f / ps;
}

#define TRI(a, c) A_[((a) * ((a) + 1)) / 2 + (c)]   // a >= c, static indices

__global__ __launch_bounds__(256, 4) void ipm_kernel(
    const float* __restrict__ Qg, const float* __restrict__ Bpg,
    const float* __restrict__ hg, const float* __restrict__ pg,
    float* __restrict__ out)
{
    __shared__ __align__(16) float sBp[kNB * BPST];   // 20736 B (block-shared, RO)
    __shared__ __align__(16) float sQ[40 * QST];      //  7040 B (block-shared, RO)
    __shared__ float sLT[4][148];                     //  2368 B (per-wave)
    __shared__ float sD[4][148];                      //  2368 B
    __shared__ __align__(16) float sU[4][40];
    __shared__ __align__(16) float sUp[4][48];
    __shared__ __align__(16) float sDup[4][48];       // total 34688 B

    const int tid = threadIdx.x;
    const int w = tid >> 6;
    const int t = tid & 63;
    const int e = blockIdx.x * 4 + w;

    for (int i = tid; i < kNB * BPST / 4; i += 256)
        reinterpret_cast<float4*>(sBp)[i] = reinterpret_cast<const float4*>(Bpg)[i];
    for (int i = tid; i < 40 * QST; i += 256) {
        int r = i / QST, c = i % QST;
        sQ[i] = (c < 40) ? Qg[r * 40 + c] : 0.f;
    }
    if (t < 8) { sUp[w][t * 6 + 5] = 0.f; sDup[w][t * 6 + 5] = 0.f; }
    __syncthreads();

    const int li = t & 7, lk = t >> 3;
    const int pp = li * 6 + lk;                       // slot of col t (valid t<40)

    float u_r = 0.f, du_r = 0.f;
    const float p_r = (t < 40) ? pg[e * 40 + t] : 0.f;
    const float h0 = hg[t], h1 = hg[64 + t], h2 = (t < 20) ? hg[128 + t] : 0.f;
    float s0 = 1.f, s1 = 1.f, s2 = 1.f, l0 = 1.f, l1 = 1.f, l2 = 1.f;

    float* lt_  = sLT[w];
    float* dd_  = sD[w];
    float* uu   = sU[w];
    float* up   = sUp[w];
    float* dup  = sDup[w];

#pragma unroll 1
    for (int it = 0; it < kITERS; ++it) {
        // (A) stage u
        if (t < 40) { uu[t] = u_r; up[pp] = u_r; }

        // (C) rp = G u + s - h
        float g0, g1, g2 = 0.f;
        if (t < 40) g0 = u_r; else g0 = rowdot48(&sBp[(t - 40) * BPST], up);
        g1 = rowdot48(&sBp[(t + 24) * BPST], up);
        if (t < 20) g2 = rowdot48(&sBp[(t + 88) * BPST], up);
        const float rp0 = g0 + s0 - h0, rp1 = g1 + s1 - h1, rp2 = g2 + s2 - h2;

        // (D) mu
        float part = s0 * l0 + s1 * l1 + ((t < 20) ? s2 * l2 : 0.f);
        const float mu = waveSum(part) * (1.f / 148.f);

        // (E) rc, d, lam+tmp   (exact IEEE division)
        const float is0 = 1.f / s0, is1 = 1.f / s1, is2 = 1.f / s2;
        const float rc0 = kSIGMA * mu - s0 * l0;
        const float rc1 = kSIGMA * mu - s1 * l1;
        const float rc2 = kSIGMA * mu - s2 * l2;
        const float t0 = (rc0 + l0 * rp0) * is0;
        const float t1 = (rc1 + l1 * rp1) * is1;
        const float t2 = (rc2 + l2 * rp2) * is2;
        lt_[t] = l0 + t0; lt_[64 + t] = l1 + t1; if (t < 20) lt_[128 + t] = l2 + t2;
        dd_[t] = l0 * is0; dd_[64 + t] = l1 * is1; if (t < 20) dd_[128 + t] = l2 * is2;

        // (F) rhs = -(p + uQ + (lam+tmp)G)
        float rhs_r = 0.f;
        if (t < 40) {
            float acc = p_r + l0 + t0;
            const float* qrow = &sQ[t * QST];
#pragma unroll
            for (int m = 0; m < 40; m += 4) {
                float4 q4 = *reinterpret_cast<const float4*>(qrow + m);
                float4 u4 = *reinterpret_cast<const float4*>(uu + m);
                acc = fmaf(q4.x, u4.x, acc); acc = fmaf(q4.y, u4.y, acc);
                acc = fmaf(q4.z, u4.z, acc); acc = fmaf(q4.w, u4.w, acc);
            }
#pragma unroll 4
            for (int j = 0; j < kNB; ++j)
                acc = fmaf(lt_[40 + j], sBp[j * BPST + pp], acc);
            rhs_r = -acc;
        }

        // (G) H = Q + diag(d[:40]) + B^T diag(d[40:]) B ; lower blocks a>=c only
        float A_[15];
#pragma unroll
        for (int a = 0; a < 5; ++a)
#pragma unroll
            for (int c = 0; c <= a; ++c)
                TRI(a, c) = sQ[(li + 8 * a) * QST + (lk + 8 * c)];
        if (li == lk) {
#pragma unroll
            for (int a = 0; a < 5; ++a) TRI(a, a) += dd_[li + 8 * a];
        }
#pragma unroll
        for (int g = 0; g < 5; ++g) {
            const int na = g + 1;
            const int lo = 24 * g;
            const int hi = (g < 4) ? 24 * (g + 1) : 108;
#pragma unroll 4
            for (int j = lo; j < hi; ++j) {
                const float ddj = dd_[40 + j];
                const float* br = &sBp[j * BPST];
                float bi[5], bk[5];
#pragma unroll
                for (int a = 0; a < na; ++a) { bi[a] = br[li * 6 + a]; bk[a] = br[lk * 6 + a]; }
#pragma unroll
                for (int a = 0; a < na; ++a) {
                    const float f = ddj * bi[a];
#pragma unroll
                    for (int c = 0; c <= a; ++c) TRI(a, c) = fmaf(f, bk[c], TRI(a, c));
                }
            }
        }

        // (H) register LDL^T in 2D lane layout. Columns stay RAW (= L*d);
        // the k-th diagonal (at lane (k8,k8)) is overwritten with r = 1/d_k.
#pragma unroll
        for (int kc = 0; kc < 5; ++kc) {
#pragma unroll 1
            for (int k8 = 0; k8 < 8; ++k8) {
                const float piv = readlane_f(TRI(kc, kc), 9 * k8);
                const float r = safe_rcp(piv);
                float colv[5], rowv[5];
#pragma unroll
                for (int a = kc; a < 5; ++a) colv[a] = __shfl(TRI(a, kc), li + 8 * k8, 64);
#pragma unroll
                for (int c = kc; c < 5; ++c) rowv[c] = __shfl(TRI(c, kc), lk + 8 * k8, 64);
                colv[kc] = (li > k8) ? colv[kc] : 0.f;   // rows  <= k give no update
                rowv[kc] = (lk > k8) ? rowv[kc] : 0.f;   // cols  <= k stay raw
#pragma unroll
                for (int c = kc; c < 5; ++c) rowv[c] *= r;
#pragma unroll
                for (int a = kc; a < 5; ++a)
#pragma unroll
                    for (int c = kc; c <= a; ++c)
                        TRI(a, c) = fmaf(-colv[a], rowv[c], TRI(a, c));
                if (li == k8 && lk == k8) TRI(kc, kc) = r;
            }
        }

        // (I) forward solve: y_k = rhs_k - sum_{j<k} raw_kj * w_j ; w_k = y_k * r_k
        float r8[5], y8[5], fa[5];
#pragma unroll
        for (int a = 0; a < 5; ++a) { r8[a] = __shfl(rhs_r, li + 8 * a, 64); fa[a] = 0.f; }
#pragma unroll
        for (int kc = 0; kc < 5; ++kc) {
#pragma unroll 1
            for (int k8 = 0; k8 < 8; ++k8) {
                float red = fa[kc];
                red += __shfl_xor(red, 8); red += __shfl_xor(red, 16); red += __shfl_xor(red, 32);
                const float wk = readlane_f((r8[kc] - red) * TRI(kc, kc), 9 * k8);
                if (lk == k8) {
#pragma unroll
                    for (int a = kc; a < 5; ++a) fa[a] = fmaf(TRI(a, kc), wk, fa[a]);
                }
                if (li == k8) y8[kc] = wk;               // stores w_k (= y_k / d_k)
            }
        }
        // backward solve: x_j = w_j - r_j * sum_{i>j} raw_ij * x_i
        float ba[5];
#pragma unroll
        for (int c = 0; c < 5; ++c) ba[c] = 0.f;
#pragma unroll
        for (int jc = 4; jc >= 0; --jc) {
#pragma unroll 1
            for (int j8 = 7; j8 >= 0; --j8) {
                float red = ba[jc];
                red += __shfl_xor(red, 1); red += __shfl_xor(red, 2); red += __shfl_xor(red, 4);
                const float xj = readlane_f(fmaf(-TRI(jc, jc), red, y8[jc]), 9 * j8);
                if (li == j8) {
#pragma unroll
                    for (int c = 0; c <= jc; ++c) ba[c] = fmaf(TRI(jc, c), xj, ba[c]);
                }
                if (t == jc * 8 + j8) du_r = xj;
            }
        }

        // (J) Gdu, ds, dlam, step, updates
        if (t < 40) dup[pp] = du_r;
        float q0, q1, q2 = 0.f;
        if (t < 40) q0 = du_r; else q0 = rowdot48(&sBp[(t - 40) * BPST], dup);
        q1 = rowdot48(&sBp[(t + 24) * BPST], dup);
        if (t < 20) q2 = rowdot48(&sBp[(t + 88) * BPST], dup);

        const float ds0 = -rp0 - q0, ds1 = -rp1 - q1, ds2 = -rp2 - q2;
        const float dl0 = (rc0 + l0 * (rp0 + q0)) * is0;
        const float dl1 = (rc1 + l1 * (rp1 + q1)) * is1;
        const float dl2 = (rc2 + l2 * (rp2 + q2)) * is2;

        float am = kBIG;
        am = fminf(am, (ds0 < 0.f) ? (-s0 / ds0) : kBIG);
        am = fminf(am, (dl0 < 0.f) ? (-l0 / dl0) : kBIG);
        am = fminf(am, (ds1 < 0.f) ? (-s1 / ds1) : kBIG);
        am = fminf(am, (dl1 < 0.f) ? (-l1 / dl1) : kBIG);
        if (t < 20) {
            am = fminf(am, (ds2 < 0.f) ? (-s2 / ds2) : kBIG);
            am = fminf(am, (dl2 < 0.f) ? (-l2 / dl2) : kBIG);
        }
        am = waveMin(am);
        const float alpha = fminf(1.f, 0.99f * am);

        if (t < 40) u_r = fmaf(alpha, du_r, u_r);
        s0 = fmaf(alpha, ds0, s0); l0 = fmaf(alpha, dl0, l0);
        s1 = fmaf(alpha, ds1, s1); l1 = fmaf(alpha, dl1, l1);
        if (t < 20) { s2 = fmaf(alpha, ds2, s2); l2 = fmaf(alpha, dl2, l2); }
    }

    // epilogue
    if (t < 40) uu[t] = u_r;
    float qv = 0.f;
    if (t < 40) {
        float uq = 0.f;
        const float* qrow = &sQ[t * QST];
#pragma unroll
        for (int m = 0; m < 40; m += 4) {
            float4 q4 = *reinterpret_cast<const float4*>(qrow + m);
            float4 u4 = *reinterpret_cast<const float4*>(uu + m);
            uq = fmaf(q4.x, u4.x, uq); uq = fmaf(q4.y, u4.y, uq);
            uq = fmaf(q4.z, u4.z, uq); uq = fmaf(q4.w, u4.w, uq);
        }
        qv = u_r * (0.5f * uq + p_r);
    }
    qv = waveSum(qv);
    if (t == 0) { out[e] = qv; out[kBATCH + e] = u_r; }
}

// ---------------------------------------------------------------------------
extern "C" void kernel_launch(void* const* d_in, const int* in_sizes, int n_in,
                              void* d_out, int out_size, void* d_ws, size_t ws_size,
                              hipStream_t stream) {
    const float* x  = (const float*)d_in[0];
    const float* W1 = (const float*)d_in[1];
    const float* b1 = (const float*)d_in[2];
    const float* W2 = (const float*)d_in[3];
    const float* b2 = (const float*)d_in[4];
    const float* L  = (const float*)d_in[5];
    const float* LP = (const float*)d_in[6];
    const float* LR = (const float*)d_in[7];
    const float* A  = (const float*)d_in[8];
    const float* Bm = (const float*)d_in[9];
    const float* u0 = (const float*)d_in[10];
    const float* s0 = (const float*)d_in[11];
    float* out = (float*)d_out;
    float* ws  = (float*)d_ws;

    float* Qg  = ws;           // 1600
    float* Bpg = ws + 1600;    // 108*48 = 5184
    float* hg  = ws + 6784;    // 148
    float* pg  = ws + 6944;    // 4096*40

    setup_kernel<<<1, 256, 0, stream>>>(L, LP, LR, A, Bm, u0, s0, Qg, Bpg, hg);
    mlp_kernel<<<kBATCH, 64, 0, stream>>>(x, W1, b1, W2, b2, pg);
    ipm_kernel<<<kBATCH / 4, 256, 0, stream>>>(Qg, Bpg, hg, pg, out);
}